// Round 4
// baseline (235.775 us; speedup 1.0000x reference)
//
#include <hip/hip_runtime.h>

// cumprod along dim 1 of (ROWS, N) fp32, row-major.
// Persistent blocks + row-level register double-buffering.
//
// Grid = n_rows/RPB = 1024 blocks of 512 threads -> exactly 4 blocks/CU,
// all resident for the whole kernel (no block turnover). Each block scans
// RPB=4 consecutive rows; while row r is being scanned, row r+1's loads
// are already in flight (the vmcnt wait lands after r's scan+store).
// This keeps the HBM pipe busy during the serial shuffle-scan phase,
// which profiling showed was idling the memory system (2.5 TB/s with no
// saturated pipe across three structurally different kernels).
//
// Per row: wave w owns elements [w*1024,(w+1)*1024); lane l holds quads
// at (v*64+l)*4 -> loads and stores natively coalesced. One barrier per
// row to exchange 8 wave totals via parity-double-buffered wsum.

#define N    8192
#define T    512
#define NW   (T / 64)          // 8 waves per block
#define QV   (N / (T * 4))     // 4 quad-iterations per thread
#define RPB  4                 // rows per block -> grid 1024 = 4 blocks/CU

typedef float f32x4 __attribute__((ext_vector_type(4)));

__global__ __launch_bounds__(T) void cumprod_rows_kernel(
    const float* __restrict__ x, float* __restrict__ out, int n_rows)
{
    __shared__ float wsum[2][NW];   // parity-buffered per row (1 barrier/row)

    const int tid  = threadIdx.x;
    const int lane = tid & 63;
    const int wid  = tid >> 6;

    const size_t base = (size_t)blockIdx.x * RPB * N + (size_t)wid * (N / NW);
    const float* __restrict__ xr   = x   + base;
    float*       __restrict__ outr = out + base;

    f32x4 A[QV];
#pragma unroll
    for (int v = 0; v < QV; ++v)
        A[v] = *reinterpret_cast<const f32x4*>(xr + (v * 64 + lane) * 4);

#pragma unroll
    for (int r = 0; r < RPB; ++r) {
        // ---- prefetch next row while we scan this one ----
        f32x4 B[QV];
        if (r + 1 < RPB) {
            const float* __restrict__ xn = xr + (size_t)(r + 1) * N;
#pragma unroll
            for (int v = 0; v < QV; ++v)
                B[v] = *reinterpret_cast<const f32x4*>(xn + (v * 64 + lane) * 4);
        }

        // ---- scan row r (register-resident) ----
        float carry = 1.0f;
        float coef[QV];
#pragma unroll
        for (int v = 0; v < QV; ++v) {
            A[v].y *= A[v].x;
            A[v].z *= A[v].y;
            A[v].w *= A[v].z;
            float inc = A[v].w;
#pragma unroll
            for (int off = 1; off < 64; off <<= 1) {
                const float o = __shfl_up(inc, off, 64);
                if (lane >= off) inc *= o;
            }
            float ex = __shfl_up(inc, 1, 64);
            if (lane == 0) ex = 1.0f;
            coef[v] = carry * ex;
            carry  *= __shfl(inc, 63, 64);
        }

        // ---- exchange wave totals (parity buffer; 1 barrier per row) ----
        if (lane == 63) wsum[r & 1][wid] = carry;
        __syncthreads();

        float wpre = 1.0f;
#pragma unroll
        for (int w = 0; w < NW - 1; ++w)
            if (w < wid) wpre *= wsum[r & 1][w];

        // ---- coalesced nontemporal stores for row r ----
        float* __restrict__ outrr = outr + (size_t)r * N;
#pragma unroll
        for (int v = 0; v < QV; ++v) {
            const float f = wpre * coef[v];
            f32x4 o = A[v];
            o.x *= f; o.y *= f; o.z *= f; o.w *= f;
            __builtin_nontemporal_store(
                o, reinterpret_cast<f32x4*>(outrr + (v * 64 + lane) * 4));
        }

        // ---- rotate buffers (fully unrolled -> register renames, no copies) ----
        if (r + 1 < RPB) {
#pragma unroll
            for (int v = 0; v < QV; ++v) A[v] = B[v];
        }
    }
}

extern "C" void kernel_launch(void* const* d_in, const int* in_sizes, int n_in,
                              void* d_out, int out_size, void* d_ws, size_t ws_size,
                              hipStream_t stream)
{
    const float* x   = (const float*)d_in[0];
    float*       out = (float*)d_out;
    const int n_rows = in_sizes[0] / N;     // 4096
    cumprod_rows_kernel<<<n_rows / RPB, T, 0, stream>>>(x, out, n_rows);
}

// Round 5
// 232.705 us; speedup vs baseline: 1.0132x; 1.0132x over previous
//
#include <hip/hip_runtime.h>

// cumprod along dim 1 of (ROWS, N) fp32, row-major.
// DPP-based scan: cross-lane work moved off the DS pipe onto VALU.
//
// One 256-thread block (4 waves) per row; wave w owns a contiguous
// 2048-elem segment. Within a segment, group v (=0..7) is 256 contiguous
// elements: lane l holds the quad at [v*256 + l*4]  -> every load/store
// instruction is 64 lanes x 16 B = 1 KB contiguous (perfectly coalesced).
//
// Scan per group: in-quad serial (3 muls) -> quad total t; exclusive
// wave-scan of t = one shfl_up lane-shift (the ONLY ds_bpermute; all 8
// are independent and issue together) followed by the canonical gfx9
// 6-step DPP multiply-scan (row_shr:1/2/4/8, row_bcast:15, row_bcast:31)
// with identity 1.0 injected via update_dpp's `old` operand -> pure VALU,
// no lgkmcnt waits. Group totals propagate via v_readlane (scalar).
// All 8 loads per thread issue up front (32 KB in flight per block)
// before any dependent wait -> max memory-level parallelism.
// One 16 B LDS exchange + one barrier per row (4 waves only).

#define N    8192
#define T    256             // 4 waves per block
#define NW   (T / 64)        // 4
#define SEG  (N / NW)        // 2048 elems per wave
#define QV   (SEG / 256)     // 8 groups of 256 elems per wave

typedef float f32x4 __attribute__((ext_vector_type(4)));

__device__ __forceinline__ float readlane63(float x) {
    return __builtin_bit_cast(float,
        __builtin_amdgcn_readlane(__builtin_bit_cast(int, x), 63));
}

// DPP-selected value of x; lanes not written (masked / invalid source)
// yield the multiplicative identity 1.0.
template<int CTRL, int RM, int BM>
__device__ __forceinline__ float dpp_id1(float x) {
    int r = __builtin_amdgcn_update_dpp(
        __builtin_bit_cast(int, 1.0f), __builtin_bit_cast(int, x),
        CTRL, RM, BM, false);
    return __builtin_bit_cast(float, r);
}

// Wave64 inclusive product-scan, all on the VALU pipe (gfx9 DPP sequence).
__device__ __forceinline__ float wave_scan_mul(float x) {
    x *= dpp_id1<0x111, 0xf, 0xf>(x);   // row_shr:1
    x *= dpp_id1<0x112, 0xf, 0xf>(x);   // row_shr:2
    x *= dpp_id1<0x114, 0xf, 0xf>(x);   // row_shr:4
    x *= dpp_id1<0x118, 0xf, 0xf>(x);   // row_shr:8
    x *= dpp_id1<0x142, 0xa, 0xf>(x);   // row_bcast:15 -> rows 1,3
    x *= dpp_id1<0x143, 0xc, 0xf>(x);   // row_bcast:31 -> rows 2,3
    return x;
}

__global__ __launch_bounds__(T) void cumprod_rows_kernel(
    const float* __restrict__ x, float* __restrict__ out, int n_rows)
{
    __shared__ float wsum[NW];

    const int row = blockIdx.x;
    if (row >= n_rows) return;
    const int tid  = threadIdx.x;
    const int lane = tid & 63;
    const int wid  = tid >> 6;

    const size_t base = (size_t)row * N + (size_t)wid * SEG;
    const float* __restrict__ xr   = x   + base;
    float*       __restrict__ outr = out + base;

    // ---- all loads up front: 8 coalesced dwordx4 per thread ----
    f32x4 d[QV];
#pragma unroll
    for (int v = 0; v < QV; ++v)
        d[v] = *reinterpret_cast<const f32x4*>(xr + v * 256 + lane * 4);

    // ---- in-quad scans + quad totals (independent across v) ----
    float t[QV];
#pragma unroll
    for (int v = 0; v < QV; ++v) {
        d[v].y *= d[v].x;
        d[v].z *= d[v].y;
        d[v].w *= d[v].z;
        t[v] = d[v].w;
    }

    // ---- lane-shift operands: the only DS ops, all independent ----
    float ep[QV];
#pragma unroll
    for (int v = 0; v < QV; ++v) {
        const float e = __shfl_up(t[v], 1, 64);
        ep[v] = (lane == 0) ? 1.0f : e;
    }

    // ---- exclusive wave-scans (DPP) + serial scalar carry across v ----
    float carry = 1.0f;
    float coef[QV];
#pragma unroll
    for (int v = 0; v < QV; ++v) {
        const float exc = wave_scan_mul(ep[v]);  // prod of t over lanes < l
        coef[v] = carry * exc;
        carry  *= readlane63(exc * t[v]);        // group total (uniform)
    }
    // carry == product of this wave's whole 2048-elem segment

    // ---- one tiny barrier: exchange 4 wave totals ----
    if (lane == 0) wsum[wid] = carry;
    __syncthreads();

    float wpre = 1.0f;
#pragma unroll
    for (int w = 0; w < NW - 1; ++w)
        if (w < wid) wpre *= wsum[w];

    // ---- apply prefixes, coalesced nontemporal stores ----
#pragma unroll
    for (int v = 0; v < QV; ++v) {
        const float f = wpre * coef[v];
        f32x4 o = d[v];
        o.x *= f; o.y *= f; o.z *= f; o.w *= f;
        __builtin_nontemporal_store(
            o, reinterpret_cast<f32x4*>(outr + v * 256 + lane * 4));
    }
}

extern "C" void kernel_launch(void* const* d_in, const int* in_sizes, int n_in,
                              void* d_out, int out_size, void* d_ws, size_t ws_size,
                              hipStream_t stream)
{
    const float* x   = (const float*)d_in[0];
    float*       out = (float*)d_out;
    const int n_rows = in_sizes[0] / N;   // 4096
    cumprod_rows_kernel<<<n_rows, T, 0, stream>>>(x, out, n_rows);
}